// Round 1
// baseline (405.998 us; speedup 1.0000x reference)
//
#include <hip/hip_runtime.h>
#include <hip/hip_bf16.h>
#include <cstdint>
#include <cstddef>

#define NB 8
#define CIN 256
#define HWX 4096
#define CF 256
#define CA 128
#define CT 384

typedef __attribute__((ext_vector_type(8))) short short8;
typedef __attribute__((ext_vector_type(4))) float f32x4;
typedef __attribute__((ext_vector_type(4))) unsigned int u32x4;

// workspace layout (bytes)
#define OFF_W    0                              // 384*256 fp32 folded weights
#define OFF_BIAS (CT*CIN*4)                     // 384 fp32 folded bias
#define OFF_FEAT (OFF_BIAS + 2048)              // [n][256][4096] bf16
#define OFF_QHI  (OFF_FEAT + NB*CF*HWX*2)       // [n][4096][128] bf16 (hi part)
#define OFF_QLO  (OFF_QHI + NB*HWX*CA*2)        // [n][4096][128] bf16 (lo part)

__device__ inline unsigned short bf16_bits(float f) {
  __hip_bfloat16 h = __float2bfloat16(f);
  return __builtin_bit_cast(unsigned short, h);
}
__device__ inline float bf16_to_f(unsigned short u) {
  __hip_bfloat16 h = __builtin_bit_cast(__hip_bfloat16, u);
  return __bfloat162float(h);
}

// async global->LDS, 16B per lane. LDS side is wave-uniform base + lane*16,
// so callers must arrange lane-linear LDS layout (swizzle goes on the global side).
__device__ inline void g2l16(const void* g, void* l) {
  __builtin_amdgcn_global_load_lds(
      (const __attribute__((address_space(1))) unsigned int*)g,
      (__attribute__((address_space(3))) unsigned int*)l, 16, 0, 0);
}

// ---------------- kernel 1: fold BN into weights ----------------
__global__ __launch_bounds__(256) void fold_bn_k(
    const float* __restrict__ rw, const float* __restrict__ rg,
    const float* __restrict__ rb, const float* __restrict__ rm, const float* __restrict__ rv,
    const float* __restrict__ aw, const float* __restrict__ ag,
    const float* __restrict__ ab2, const float* __restrict__ am, const float* __restrict__ av,
    float* __restrict__ wf, float* __restrict__ bias) {
  int o = blockIdx.x, k = threadIdx.x;
  const float* wsrc; float g, b, m, v;
  if (o < CF) { wsrc = rw + (size_t)o*CIN; g = rg[o]; b = rb[o]; m = rm[o]; v = rv[o]; }
  else { int oa = o - CF; wsrc = aw + (size_t)oa*CIN; g = ag[oa]; b = ab2[oa]; m = am[oa]; v = av[oa]; }
  float inv = g / sqrtf(v + 1e-5f);
  wf[(size_t)o*CIN + k] = wsrc[k] * inv;
  if (k == 0) bias[o] = b - m*inv;
}

// ---------------- kernel 2: fp32 conv(1x1)+BN+ReLU GEMM ----------------
// grid 768 = 8n * 3 och-tiles(128) * 32 pos-tiles(128); 256 thr, 8x8 per thread
__global__ __launch_bounds__(256) void conv_k(
    const float* __restrict__ x, const float* __restrict__ wf,
    const float* __restrict__ bias, unsigned short* __restrict__ feat,
    unsigned short* __restrict__ qhi, unsigned short* __restrict__ qlo) {
  __shared__ float w_s[16][132];   // [k][oc], padded
  __shared__ float x_s[16][132];   // [k][pos], padded
  int b = blockIdx.x;
  int n = b / 96, rem = b % 96;
  int ot = rem / 32, pt = rem % 32;
  int oc0 = ot*128, p0 = pt*128;
  int t = threadIdx.x, ty = t >> 4, tx = t & 15;
  const float* xn = x + (size_t)n*CIN*HWX;
  float acc[8][8];
  #pragma unroll
  for (int i=0;i<8;i++)
    #pragma unroll
    for (int j=0;j<8;j++) acc[i][j]=0.f;

  for (int k0=0; k0<CIN; k0+=16) {
    __syncthreads();
    #pragma unroll
    for (int pass=0; pass<2; pass++) {
      int idx = pass*256+t, oc = idx>>2, kq = idx&3;
      f32x4 wv = *(const f32x4*)(wf + (size_t)(oc0+oc)*CIN + k0 + kq*4);
      w_s[kq*4+0][oc]=wv.x; w_s[kq*4+1][oc]=wv.y; w_s[kq*4+2][oc]=wv.z; w_s[kq*4+3][oc]=wv.w;
    }
    #pragma unroll
    for (int pass=0; pass<2; pass++) {
      int idx = pass*256+t, row = idx>>5, cc = idx&31;
      f32x4 xv = *(const f32x4*)(xn + (size_t)(k0+row)*HWX + p0 + cc*4);
      *(f32x4*)&x_s[row][cc*4] = xv;
    }
    __syncthreads();
    #pragma unroll
    for (int kk=0; kk<16; kk++) {
      float a[8], bb[8];
      *(f32x4*)&a[0]  = *(const f32x4*)&w_s[kk][ty*8];
      *(f32x4*)&a[4]  = *(const f32x4*)&w_s[kk][ty*8+4];
      *(f32x4*)&bb[0] = *(const f32x4*)&x_s[kk][tx*8];
      *(f32x4*)&bb[4] = *(const f32x4*)&x_s[kk][tx*8+4];
      #pragma unroll
      for (int i=0;i<8;i++)
        #pragma unroll
        for (int j=0;j<8;j++) acc[i][j] = fmaf(a[i], bb[j], acc[i][j]);
    }
  }

  int posb = p0 + tx*8;
  float bs[8];
  #pragma unroll
  for (int i=0;i<8;i++) bs[i] = bias[oc0 + ty*8 + i];

  if (oc0 < CF) {
    // feat path: [n][c][pos] bf16
    #pragma unroll
    for (int i=0;i<8;i++) {
      int oc = oc0 + ty*8 + i;
      alignas(16) unsigned short u[8];
      #pragma unroll
      for (int j=0;j<8;j++) {
        float vv = fmaxf(acc[i][j] + bs[i], 0.f);
        u[j] = bf16_bits(vv);
      }
      *(u32x4*)(feat + (size_t)n*CF*HWX + (size_t)oc*HWX + posb) = *(const u32x4*)u;
    }
  } else {
    // q path: [n][pos][c] bf16 hi/lo split (fp32-accurate energy later)
    int cb = oc0 - CF + ty*8;
    #pragma unroll
    for (int j=0;j<8;j++) {
      alignas(16) unsigned short uh[8], ul[8];
      #pragma unroll
      for (int i=0;i<8;i++) {
        float vv = fmaxf(acc[i][j] + bs[i], 0.f);
        unsigned short h = bf16_bits(vv);
        uh[i] = h;
        ul[i] = bf16_bits(vv - bf16_to_f(h));
      }
      size_t base = ((size_t)n*HWX + posb + j)*CA + cb;
      *(u32x4*)(qhi + base) = *(const u32x4*)uh;
      *(u32x4*)(qlo + base) = *(const u32x4*)ul;
    }
  }
}

// ---------------- kernel 3: flash attention ----------------
// grid 512: n = bid&7 (XCD affinity), it = bid>>3; BM=64 i-rows, 4 waves x 16 rows
__global__ __launch_bounds__(256, 2) void flash_k(
    const unsigned short* __restrict__ qhi, const unsigned short* __restrict__ qlo,
    const unsigned short* __restrict__ feat, const float* __restrict__ mask,
    float* __restrict__ out) {
  __shared__ alignas(16) unsigned short sQh[64*128];  // j-tile q hi, octet-swizzled rows
  __shared__ alignas(16) unsigned short sQl[64*128];
  __shared__ alignas(16) unsigned short sF[256*64];   // feat tile [c][j], octet-swizzled
  __shared__ alignas(16) unsigned short sP[4*16*72];  // per-wave P, padded stride 72
  __shared__ float sM[64];
  int b = blockIdx.x;
  int n = b & 7, it = b >> 3;
  int i0 = it * 64;
  int t = threadIdx.x;
  int w = t >> 6, lane = t & 63, quad = lane >> 4, col = lane & 15;
  const unsigned short* qh_n = qhi + (size_t)n*HWX*CA;
  const unsigned short* ql_n = qlo + (size_t)n*HWX*CA;
  const unsigned short* f_n  = feat + (size_t)n*CF*HWX;
  const float* m_n = mask + (size_t)n*HWX;

  // preload A fragments (q rows of this wave's 16 i's), constant over j-loop
  short8 ah[4], al[4];
  {
    int arow = i0 + w*16 + col;
    #pragma unroll
    for (int ks=0; ks<4; ks++) {
      ah[ks] = *(const short8*)(qh_n + (size_t)arow*CA + ks*32 + quad*8);
      al[ks] = *(const short8*)(ql_n + (size_t)arow*CA + ks*32 + quad*8);
    }
  }
  f32x4 fzero = {0.f,0.f,0.f,0.f};
  f32x4 o[16];
  #pragma unroll
  for (int i=0;i<16;i++) o[i] = fzero;
  float mrun[4], lrun[4];
  #pragma unroll
  for (int r=0;r<4;r++){ mrun[r] = -INFINITY; lrun[r] = 0.f; }
  const float inv_s = 1.0f/(1e-8f + sqrtf(128.0f));
  const int rloc = t >> 4, oct16 = t & 15;
  const int frow = t >> 3, oct8 = t & 7;

  for (int j0 = 0; j0 < HWX; j0 += 64) {
    __syncthreads();
    // ---- stage j-tile: q hi/lo [64][128] and feat [256][64], XOR-octet swizzle on the
    // ---- GLOBAL address (LDS must be lane-linear for global_load_lds)
    #pragma unroll
    for (int c=0;c<4;c++) {
      int row = c*16 + rloc;
      int og = oct16 ^ (row & 15);
      g2l16(qh_n + (size_t)(j0+row)*CA + og*8, &sQh[(size_t)row*128 + oct16*8]);
    }
    #pragma unroll
    for (int c=0;c<4;c++) {
      int row = c*16 + rloc;
      int og = oct16 ^ (row & 15);
      g2l16(ql_n + (size_t)(j0+row)*CA + og*8, &sQl[(size_t)row*128 + oct16*8]);
    }
    #pragma unroll
    for (int p=0;p<8;p++) {
      int row = p*32 + frow;
      int og = oct8 ^ (row & 7);
      g2l16(f_n + (size_t)row*HWX + j0 + og*8, &sF[(size_t)row*64 + oct8*8]);
    }
    if (t < 64) sM[t] = m_n[j0 + t];
    __syncthreads();

    // ---- QK^T: S[16 i x 64 j] per wave, split-precision (hh + lh + hl)
    f32x4 s[4];
    #pragma unroll
    for (int jt=0;jt<4;jt++) s[jt] = fzero;
    #pragma unroll
    for (int ks=0; ks<4; ks++) {
      #pragma unroll
      for (int jt=0;jt<4;jt++) {
        int row = jt*16 + col;
        int slot = (ks*4 + quad) ^ (row & 15);
        short8 bh = *(const short8*)&sQh[row*128 + slot*8];
        short8 bl = *(const short8*)&sQl[row*128 + slot*8];
        s[jt] = __builtin_amdgcn_mfma_f32_16x16x32_bf16(ah[ks], bh, s[jt], 0, 0, 0);
        s[jt] = __builtin_amdgcn_mfma_f32_16x16x32_bf16(al[ks], bh, s[jt], 0, 0, 0);
        s[jt] = __builtin_amdgcn_mfma_f32_16x16x32_bf16(ah[ks], bl, s[jt], 0, 0, 0);
      }
    }

    // ---- online softmax; C/D layout: row = quad*4+r (i), col = lane&15 (j)
    float mj[4];
    #pragma unroll
    for (int jt=0;jt<4;jt++) mj[jt] = (sM[jt*16+col] - 1.f) * 1e8f;
    float sv[4][4], alpha[4];
    #pragma unroll
    for (int jt=0;jt<4;jt++)
      #pragma unroll
      for (int r=0;r<4;r++) sv[jt][r] = s[jt][r]*inv_s + mj[jt];
    #pragma unroll
    for (int r=0;r<4;r++) {
      float mx = fmaxf(fmaxf(sv[0][r],sv[1][r]), fmaxf(sv[2][r],sv[3][r]));
      mx = fmaxf(mx, __shfl_xor(mx, 1, 64));
      mx = fmaxf(mx, __shfl_xor(mx, 2, 64));
      mx = fmaxf(mx, __shfl_xor(mx, 4, 64));
      mx = fmaxf(mx, __shfl_xor(mx, 8, 64));
      float mn = fmaxf(mrun[r], mx);
      alpha[r] = __expf(mrun[r] - mn);
      mrun[r] = mn;
      float ss = 0.f;
      #pragma unroll
      for (int jt=0;jt<4;jt++) { float p = __expf(sv[jt][r] - mn); sv[jt][r] = p; ss += p; }
      ss += __shfl_xor(ss, 1, 64);
      ss += __shfl_xor(ss, 2, 64);
      ss += __shfl_xor(ss, 4, 64);
      ss += __shfl_xor(ss, 8, 64);
      lrun[r] = lrun[r]*alpha[r] + ss;
    }
    bool need = (alpha[0]!=1.f)|(alpha[1]!=1.f)|(alpha[2]!=1.f)|(alpha[3]!=1.f);
    if (__ballot(need)) {
      #pragma unroll
      for (int ct=0;ct<16;ct++) {
        o[ct][0]*=alpha[0]; o[ct][1]*=alpha[1]; o[ct][2]*=alpha[2]; o[ct][3]*=alpha[3];
      }
    }

    // ---- P: C/D layout -> A-operand layout via per-wave LDS buffer
    unsigned short* sPw = &sP[w*1152];
    #pragma unroll
    for (int jt=0;jt<4;jt++)
      #pragma unroll
      for (int r=0;r<4;r++)
        sPw[(quad*4+r)*72 + jt*16 + col] = bf16_bits(sv[jt][r]);
    asm volatile("s_waitcnt lgkmcnt(0)" ::: "memory");  // same-wave RAW on sPw

    // ---- PV: O[16 i x 256 c] += P[16 x 64] * featT[64 x 256]
    #pragma unroll
    for (int ks2=0; ks2<2; ks2++) {
      short8 aP = *(const short8*)&sPw[col*72 + ks2*32 + quad*8];
      #pragma unroll
      for (int ct=0;ct<16;ct++) {
        int c = ct*16 + col;
        int slot = (ks2*4 + quad) ^ (c & 7);
        short8 bF = *(const short8*)&sF[c*64 + slot*8];
        o[ct] = __builtin_amdgcn_mfma_f32_16x16x32_bf16(aP, bF, o[ct], 0, 0, 0);
      }
    }
  }

  // ---- epilogue: divide by l, multiply by mask[i], store fp32
  float minv[4];
  #pragma unroll
  for (int r=0;r<4;r++) minv[r] = m_n[i0 + w*16 + quad*4 + r] / lrun[r];
  #pragma unroll
  for (int ct=0;ct<16;ct++) {
    f32x4 v;
    v[0]=o[ct][0]*minv[0]; v[1]=o[ct][1]*minv[1]; v[2]=o[ct][2]*minv[2]; v[3]=o[ct][3]*minv[3];
    *(f32x4*)(out + ((size_t)n*CF + ct*16 + col)*HWX + i0 + w*16 + quad*4) = v;
  }
}

extern "C" void kernel_launch(void* const* d_in, const int* in_sizes, int n_in,
                              void* d_out, int out_size, void* d_ws, size_t ws_size,
                              hipStream_t stream) {
  const float* x    = (const float*)d_in[0];
  const float* mask = (const float*)d_in[1];
  const float* rw   = (const float*)d_in[2];
  const float* rg   = (const float*)d_in[3];
  const float* rb   = (const float*)d_in[4];
  const float* rm   = (const float*)d_in[5];
  const float* rv   = (const float*)d_in[6];
  const float* aw   = (const float*)d_in[7];
  const float* ag   = (const float*)d_in[8];
  const float* ab   = (const float*)d_in[9];
  const float* am   = (const float*)d_in[10];
  const float* av   = (const float*)d_in[11];
  float* out = (float*)d_out;
  char* ws = (char*)d_ws;
  float* wf   = (float*)(ws + OFF_W);
  float* bias = (float*)(ws + OFF_BIAS);
  unsigned short* feat = (unsigned short*)(ws + OFF_FEAT);
  unsigned short* qhi  = (unsigned short*)(ws + OFF_QHI);
  unsigned short* qlo  = (unsigned short*)(ws + OFF_QLO);

  hipLaunchKernelGGL(fold_bn_k, dim3(CT), dim3(CIN), 0, stream,
                     rw, rg, rb, rm, rv, aw, ag, ab, am, av, wf, bias);
  hipLaunchKernelGGL(conv_k, dim3(768), dim3(256), 0, stream,
                     x, wf, bias, feat, qhi, qlo);
  hipLaunchKernelGGL(flash_k, dim3(512), dim3(256), 0, stream,
                     qhi, qlo, feat, mask, out);
}